// Round 1
// baseline (221.186 us; speedup 1.0000x reference)
//
#include <hip/hip_runtime.h>
#include <hip/hip_bf16.h>

// Problem constants
#define DIM_X 256
#define DIM_E 256
#define DD    512          // DIM_X + DIM_E
#define NB    8            // batch
#define NN    2048         // sequence
#define SCALE 0.044194173824159216f   // (DIM_X+DIM_E)^-0.5

typedef __attribute__((ext_vector_type(8))) __bf16 bf16x8;
typedef __attribute__((ext_vector_type(4))) float  f32x4;

__device__ __forceinline__ unsigned short f2bf(float f) {
  union { __hip_bfloat16 h; unsigned short u; } cvt;
  cvt.h = __float2bfloat16(f);
  return cvt.u;
}

// async global->LDS 16B copy (CK-style addrspace handling: AS3 ptr is the
// low 32 bits of the flat LDS address)
__device__ __forceinline__ void async_lds16(const void* g, void* l) {
  using u32_as3 = __attribute__((address_space(3))) unsigned int;
  using u32_as1 = const __attribute__((address_space(1))) unsigned int;
  __builtin_amdgcn_global_load_lds(
      reinterpret_cast<u32_as1*>(reinterpret_cast<unsigned long long>(g)),
      reinterpret_cast<u32_as3*>(static_cast<unsigned int>(
          reinterpret_cast<unsigned long long>(l))),
      16, 0, 0);
}

// ---------------------------------------------------------------------------
// Prep kernels
// ---------------------------------------------------------------------------

// xe[r, c] = c < 256 ? x[r, c] : e[r % 2048, c-256]   (bf16, 16384 x 512)
__global__ __launch_bounds__(256) void pack_xe(const float* __restrict__ x,
                                               const float* __restrict__ e,
                                               __hip_bfloat16* __restrict__ xe) {
  long idx = ((long)blockIdx.x * 256 + threadIdx.x) * 4;  // element index
  int  c   = (int)(idx & (DD - 1));
  long r   = idx >> 9;
  const float* src = (c < DIM_X) ? (x + r * DIM_X + c)
                                 : (e + (r & (NN - 1)) * DIM_E + (c - DIM_X));
  float4 v = *(const float4*)src;
  ushort4 o;
  o.x = f2bf(v.x); o.y = f2bf(v.y); o.z = f2bf(v.z); o.w = f2bf(v.w);
  *(ushort4*)((unsigned short*)xe + idx) = o;
}

// Wqk rows 0..511 = Wq, rows 512..1023 = Wk  (bf16, 1024 x 512)
__global__ __launch_bounds__(256) void pack_w(const float* __restrict__ Wq,
                                              const float* __restrict__ Wk,
                                              __hip_bfloat16* __restrict__ Wqk) {
  long idx = ((long)blockIdx.x * 256 + threadIdx.x) * 4;
  long r   = idx >> 9;
  int  c   = (int)(idx & (DD - 1));
  const float* src = (r < DD) ? (Wq + r * DD + c) : (Wk + (r - DD) * DD + c);
  float4 v = *(const float4*)src;
  ushort4 o;
  o.x = f2bf(v.x); o.y = f2bf(v.y); o.z = f2bf(v.z); o.w = f2bf(v.w);
  *(ushort4*)((unsigned short*)Wqk + idx) = o;
}

// VT[b, t, m] = x[b, m, t]  (bf16, per batch 256 x 2048), tiled transpose
__global__ __launch_bounds__(256) void transpose_v(const float* __restrict__ x,
                                                   __hip_bfloat16* __restrict__ VT) {
  __shared__ float tile[32][33];
  const int b  = blockIdx.z;
  const int m0 = blockIdx.x * 32;
  const int t0 = blockIdx.y * 32;
  const float* xb = x + (long)b * NN * DIM_X;
#pragma unroll
  for (int k = 0; k < 4; k++) {
    int i = threadIdx.y + k * 8;
    tile[i][threadIdx.x] = xb[(long)(m0 + i) * DIM_X + t0 + threadIdx.x];
  }
  __syncthreads();
  __hip_bfloat16* vb = VT + (long)b * DIM_X * NN;
#pragma unroll
  for (int k = 0; k < 4; k++) {
    int i = threadIdx.y + k * 8;
    vb[(long)(t0 + i) * NN + m0 + threadIdx.x] =
        __float2bfloat16(tile[threadIdx.x][i]);
  }
}

// ---------------------------------------------------------------------------
// Generic B-transposed bf16 GEMM: C[M,N] = alpha * A[M,K] * B[N,K]^T
// 128x128 block tile, 4 waves (2x2), 64x64 wave tile, 16x16x32 bf16 MFMA,
// BK=32, global_load_lds width-16 staging (m97 structure).
// ---------------------------------------------------------------------------
#define TM 128
#define TN 128
#define BK 32

template <bool OUT_BF16>
__global__ __launch_bounds__(256) void gemm_bt(
    const __hip_bfloat16* __restrict__ A,  // M x K, row stride lda
    const __hip_bfloat16* __restrict__ B,  // N x K, row stride ldb
    void* __restrict__ Cv,                 // M x N, row stride ldc
    int K, int lda, int ldb, int ldc,
    long strideA, long strideB, long strideC,  // per-batch element strides
    float alpha) {
  __shared__ __hip_bfloat16 sA[TM * BK];
  __shared__ __hip_bfloat16 sB[TN * BK];

  const int tid  = threadIdx.x;
  const int lane = tid & 63;
  const int wave = tid >> 6;
  const int lm   = lane & 15;
  const int quad = lane >> 4;
  const int wm   = (wave >> 1) * 64;
  const int wn   = (wave & 1) * 64;
  const long bz  = blockIdx.z;

  const __hip_bfloat16* Ab = A + bz * strideA + (long)blockIdx.y * TM * lda;
  const __hip_bfloat16* Bb = B + bz * strideB + (long)blockIdx.x * TN * ldb;

  // staging: 512 16B-chunks per tile; chunk c covers (row=c>>2, col=(c&3)*8)
  const int c0 = tid;        // round 0: rows 0..63
  const int c1 = tid + 256;  // round 1: rows 64..127
  const int r0 = c0 >> 2, cb0 = (c0 & 3) * 8;
  const int r1 = c1 >> 2, cb1 = (c1 & 3) * 8;

  f32x4 zero = {0.f, 0.f, 0.f, 0.f};
  f32x4 acc[4][4];
#pragma unroll
  for (int i = 0; i < 4; i++)
#pragma unroll
    for (int j = 0; j < 4; j++) acc[i][j] = zero;

  for (int k0 = 0; k0 < K; k0 += BK) {
    async_lds16(Ab + (long)r0 * lda + k0 + cb0, sA + (size_t)c0 * 8);
    async_lds16(Ab + (long)r1 * lda + k0 + cb1, sA + (size_t)c1 * 8);
    async_lds16(Bb + (long)r0 * ldb + k0 + cb0, sB + (size_t)c0 * 8);
    async_lds16(Bb + (long)r1 * ldb + k0 + cb1, sB + (size_t)c1 * 8);
    __syncthreads();  // drains vmcnt (global_load_lds) + lgkm

    bf16x8 af[4], bf[4];
#pragma unroll
    for (int i = 0; i < 4; i++)
      af[i] = *(const bf16x8*)&sA[(wm + i * 16 + lm) * BK + quad * 8];
#pragma unroll
    for (int j = 0; j < 4; j++)
      bf[j] = *(const bf16x8*)&sB[(wn + j * 16 + lm) * BK + quad * 8];

#pragma unroll
    for (int i = 0; i < 4; i++)
#pragma unroll
      for (int j = 0; j < 4; j++)
        acc[i][j] = __builtin_amdgcn_mfma_f32_16x16x32_bf16(af[i], bf[j],
                                                            acc[i][j], 0, 0, 0);
    __syncthreads();
  }

  // C/D layout (16x16): col = lane&15, row = (lane>>4)*4 + reg  [m89-verified]
  const long baseRow = (long)blockIdx.y * TM + wm + quad * 4;
  const long baseCol = (long)blockIdx.x * TN + wn + lm;
  if (OUT_BF16) {
    __hip_bfloat16* Cb = (__hip_bfloat16*)Cv + bz * strideC;
#pragma unroll
    for (int i = 0; i < 4; i++)
#pragma unroll
      for (int r = 0; r < 4; r++) {
        long row = baseRow + i * 16 + r;
#pragma unroll
        for (int j = 0; j < 4; j++)
          Cb[row * ldc + baseCol + j * 16] =
              __float2bfloat16(acc[i][j][r] * alpha);
      }
  } else {
    float* Cf = (float*)Cv + bz * strideC;
#pragma unroll
    for (int i = 0; i < 4; i++)
#pragma unroll
      for (int r = 0; r < 4; r++) {
        long row = baseRow + i * 16 + r;
#pragma unroll
        for (int j = 0; j < 4; j++)
          Cf[row * ldc + baseCol + j * 16] = acc[i][j][r] * alpha;
      }
  }
}

// ---------------------------------------------------------------------------

extern "C" void kernel_launch(void* const* d_in, const int* in_sizes, int n_in,
                              void* d_out, int out_size, void* d_ws,
                              size_t ws_size, hipStream_t stream) {
  const float* x  = (const float*)d_in[0];  // (8, 2048, 256)
  const float* e  = (const float*)d_in[1];  // (2048, 256)
  const float* Wq = (const float*)d_in[2];  // (512, 512)
  const float* Wk = (const float*)d_in[3];  // (512, 512)
  float* out = (float*)d_out;               // (8, 2048, 256)

  char* ws = (char*)d_ws;
  size_t off = 0;
  auto alloc = [&](size_t bytes) {
    void* p = ws + off;
    off += (bytes + 255) & ~(size_t)255;
    return p;
  };

  __hip_bfloat16* xe  = (__hip_bfloat16*)alloc((size_t)NB * NN * DD * 2);     // 16.8 MB
  __hip_bfloat16* Wqk = (__hip_bfloat16*)alloc((size_t)2 * DD * DD * 2);      // 1 MB
  __hip_bfloat16* VT  = (__hip_bfloat16*)alloc((size_t)NB * DIM_X * NN * 2);  // 8.4 MB
  __hip_bfloat16* QK  = (__hip_bfloat16*)alloc((size_t)NB * NN * 2 * DD * 2); // 33.6 MB

  const size_t attn_full = (size_t)NB * NN * NN * 2;  // 67.1 MB
  const bool full = (off + attn_full) <= ws_size;
  __hip_bfloat16* attn =
      (__hip_bfloat16*)alloc(full ? attn_full : (size_t)NN * NN * 2);

  // --- prep ---
  pack_xe<<<8192, 256, 0, stream>>>(x, e, xe);
  pack_w<<<512, 256, 0, stream>>>(Wq, Wk, Wqk);
  transpose_v<<<dim3(NN / 32, DIM_X / 32, NB), dim3(32, 8), 0, stream>>>(x, VT);

  // --- GEMM1: QK(16384 x 1024) = xe(16384 x 512) @ Wqk(1024 x 512)^T ---
  gemm_bt<true><<<dim3((2 * DD) / TN, (NB * NN) / TM, 1), 256, 0, stream>>>(
      xe, Wqk, QK, DD, DD, DD, 2 * DD, 0, 0, 0, 1.0f);

  if (full) {
    // --- GEMM2 (batched): attn_b = Q_b @ K_b^T * SCALE, bf16 ---
    gemm_bt<true><<<dim3(NN / TN, NN / TM, NB), 256, 0, stream>>>(
        QK, QK + DD, attn, DD, 2 * DD, 2 * DD, NN,
        (long)NN * 2 * DD, (long)NN * 2 * DD, (long)NN * NN, SCALE);
    // --- GEMM3 (batched): out_b = attn_b @ VT_b^T, fp32 ---
    gemm_bt<false><<<dim3(DIM_X / TN, NN / TM, NB), 256, 0, stream>>>(
        attn, VT, out, NN, NN, NN, DIM_X,
        (long)NN * NN, (long)DIM_X * NN, (long)NN * DIM_X, 1.0f);
  } else {
    for (int b = 0; b < NB; b++) {
      const long qkOff = (long)b * NN * 2 * DD;
      gemm_bt<true><<<dim3(NN / TN, NN / TM, 1), 256, 0, stream>>>(
          QK + qkOff, QK + qkOff + DD, attn, DD, 2 * DD, 2 * DD, NN, 0, 0, 0,
          SCALE);
      gemm_bt<false><<<dim3(DIM_X / TN, NN / TM, 1), 256, 0, stream>>>(
          attn, VT + (long)b * DIM_X * NN, out + (long)b * NN * DIM_X, NN, NN,
          NN, DIM_X, 0, 0, 0, 1.0f);
    }
  }
}

// Round 2
// 154.229 us; speedup vs baseline: 1.4341x; 1.4341x over previous
//
#include <hip/hip_runtime.h>
#include <hip/hip_bf16.h>

// Problem constants
#define DIM_X 256
#define DIM_E 256
#define DD    512          // DIM_X + DIM_E
#define NB    8            // batch
#define NN    2048         // sequence
#define SCALE 0.044194173824159216f   // (DIM_X+DIM_E)^-0.5

typedef __attribute__((ext_vector_type(8))) __bf16 bf16x8;
typedef __attribute__((ext_vector_type(4))) float  f32x4;

__device__ __forceinline__ unsigned short f2bf(float f) {
  union { __hip_bfloat16 h; unsigned short u; } cvt;
  cvt.h = __float2bfloat16(f);
  return cvt.u;
}

// async global->LDS 16B copy. LDS dest must be wave-uniform base + lane*16.
__device__ __forceinline__ void async_lds16(const void* g, void* l) {
  using u32_as3 = __attribute__((address_space(3))) unsigned int;
  using u32_as1 = const __attribute__((address_space(1))) unsigned int;
  __builtin_amdgcn_global_load_lds(
      reinterpret_cast<u32_as1*>(reinterpret_cast<unsigned long long>(g)),
      reinterpret_cast<u32_as3*>(static_cast<unsigned int>(
          reinterpret_cast<unsigned long long>(l))),
      16, 0, 0);
}

// ---------------------------------------------------------------------------
// Prep kernels
// ---------------------------------------------------------------------------

// Reads x ONCE; writes xe[:, 0:256] (bf16 row-major) and VT[b][t][n] (bf16
// transposed V = x). 32x32 fp32 tile via LDS (+1 pad).
__global__ __launch_bounds__(256) void pack_xv(const float* __restrict__ x,
                                               __hip_bfloat16* __restrict__ xe,
                                               __hip_bfloat16* __restrict__ VT) {
  __shared__ float tile[32][33];
  const int tx = threadIdx.x, ty = threadIdx.y;
  const int b = blockIdx.z, n0 = blockIdx.y * 32, t0 = blockIdx.x * 32;
  const float* xb = x + ((long)b * NN + n0) * DIM_X + t0;
#pragma unroll
  for (int k = 0; k < 4; k++) {
    int i = ty + k * 8;
    tile[i][tx] = xb[(long)i * DIM_X + tx];
  }
  __syncthreads();
#pragma unroll
  for (int k = 0; k < 4; k++) {
    int i = ty + k * 8;
    xe[((long)b * NN + n0 + i) * DD + t0 + tx] = __float2bfloat16(tile[i][tx]);
    VT[((long)b * DIM_X + t0 + i) * NN + n0 + tx] =
        __float2bfloat16(tile[tx][i]);
  }
}

// xe[:, 256:512] = e broadcast over batch (bf16)
__global__ __launch_bounds__(256) void pack_e(const float* __restrict__ e,
                                              __hip_bfloat16* __restrict__ xe) {
  long idx = (long)blockIdx.x * 256 + threadIdx.x;  // one float4 per thread
  long r = idx >> 6;                                 // 64 float4 per row
  int  c = (int)(idx & 63) * 4;
  float4 v = *(const float4*)(e + (r & (NN - 1)) * DIM_E + c);
  ushort4 o;
  o.x = f2bf(v.x); o.y = f2bf(v.y); o.z = f2bf(v.z); o.w = f2bf(v.w);
  *(ushort4*)((unsigned short*)xe + r * DD + DIM_X + c) = o;
}

// Wqk rows 0..511 = Wq, rows 512..1023 = Wk  (bf16, 1024 x 512)
__global__ __launch_bounds__(256) void pack_w(const float* __restrict__ Wq,
                                              const float* __restrict__ Wk,
                                              __hip_bfloat16* __restrict__ Wqk) {
  long idx = ((long)blockIdx.x * 256 + threadIdx.x) * 4;
  long r   = idx >> 9;
  int  c   = (int)(idx & (DD - 1));
  const float* src = (r < DD) ? (Wq + r * DD + c) : (Wk + (r - DD) * DD + c);
  float4 v = *(const float4*)src;
  ushort4 o;
  o.x = f2bf(v.x); o.y = f2bf(v.y); o.z = f2bf(v.z); o.w = f2bf(v.w);
  *(ushort4*)((unsigned short*)Wqk + idx) = o;
}

// ---------------------------------------------------------------------------
// B-transposed bf16 GEMM: C[M,N] = alpha * A[M,K] * B[N,K]^T
// Templated block tile BMxBN, wave tile WTMxWTN (4 waves, 256 threads),
// 16x16x32 bf16 MFMA, BK=32, global_load_lds width-16 staging,
// XOR-swizzled LDS layout (colblk ^ ((row>>1)&3)) to kill bank conflicts.
// ---------------------------------------------------------------------------
#define BK 32

template <int BM, int BN, int WTM, int WTN, bool OUT_BF16>
__global__ __launch_bounds__(256) void gemm_bt(
    const __hip_bfloat16* __restrict__ A,  // M x K, row stride lda
    const __hip_bfloat16* __restrict__ B,  // N x K, row stride ldb
    void* __restrict__ Cv,                 // M x N, row stride ldc
    int K, int lda, int ldb, int ldc,
    long strideA, long strideB, long strideC, float alpha) {
  constexpr int IM  = WTM / 16;
  constexpr int IN  = WTN / 16;
  constexpr int NWC = BN / WTN;            // waves along N
  constexpr int CA  = BM * BK / 8;         // 16B chunks in A tile
  constexpr int CB  = BN * BK / 8;

  __shared__ __hip_bfloat16 sA[BM * BK];
  __shared__ __hip_bfloat16 sB[BN * BK];

  const int tid  = threadIdx.x;
  const int lane = tid & 63;
  const int wave = tid >> 6;
  const int lm   = lane & 15;
  const int quad = lane >> 4;
  const int wm   = (wave / NWC) * WTM;
  const int wn   = (wave % NWC) * WTN;
  const long bz  = blockIdx.z;

  const __hip_bfloat16* Ab = A + bz * strideA + (long)blockIdx.y * BM * lda;
  const __hip_bfloat16* Bb = B + bz * strideB + (long)blockIdx.x * BN * ldb;

  f32x4 acc[IM][IN];
#pragma unroll
  for (int i = 0; i < IM; i++)
#pragma unroll
    for (int j = 0; j < IN; j++) acc[i][j] = (f32x4){0.f, 0.f, 0.f, 0.f};

  for (int k0 = 0; k0 < K; k0 += BK) {
    // staging: chunk c sits at LDS offset c*16B (wave-uniform + lane*16);
    // it carries global (row=c>>2, colblk=(c&3)^swz(row)), swz(r)=(r>>1)&3
#pragma unroll
    for (int c = tid; c < CA; c += 256) {
      int row = c >> 2;
      int cb  = (c & 3) ^ ((row >> 1) & 3);
      async_lds16(Ab + (long)row * lda + k0 + cb * 8, sA + (size_t)c * 8);
    }
#pragma unroll
    for (int c = tid; c < CB; c += 256) {
      int row = c >> 2;
      int cb  = (c & 3) ^ ((row >> 1) & 3);
      async_lds16(Bb + (long)row * ldb + k0 + cb * 8, sB + (size_t)c * 8);
    }
    __syncthreads();  // drains vmcnt (global_load_lds)

    bf16x8 af[IM], bfr[IN];
#pragma unroll
    for (int i = 0; i < IM; i++) {
      int r = wm + i * 16 + lm;
      af[i] = *(const bf16x8*)&sA[r * BK + (quad ^ ((r >> 1) & 3)) * 8];
    }
#pragma unroll
    for (int j = 0; j < IN; j++) {
      int r = wn + j * 16 + lm;
      bfr[j] = *(const bf16x8*)&sB[r * BK + (quad ^ ((r >> 1) & 3)) * 8];
    }

#pragma unroll
    for (int i = 0; i < IM; i++)
#pragma unroll
      for (int j = 0; j < IN; j++)
        acc[i][j] = __builtin_amdgcn_mfma_f32_16x16x32_bf16(af[i], bfr[j],
                                                            acc[i][j], 0, 0, 0);
    __syncthreads();
  }

  // C/D layout (16x16): col = lane&15, row = (lane>>4)*4 + reg  [m89-verified]
  const long baseRow = (long)blockIdx.y * BM + wm + quad * 4;
  const long baseCol = (long)blockIdx.x * BN + wn + lm;
  if (OUT_BF16) {
    __hip_bfloat16* Cb = (__hip_bfloat16*)Cv + bz * strideC;
#pragma unroll
    for (int i = 0; i < IM; i++)
#pragma unroll
      for (int r = 0; r < 4; r++) {
        long row = baseRow + i * 16 + r;
#pragma unroll
        for (int j = 0; j < IN; j++)
          Cb[row * ldc + baseCol + j * 16] =
              __float2bfloat16(acc[i][j][r] * alpha);
      }
  } else {
    float* Cf = (float*)Cv + bz * strideC;
#pragma unroll
    for (int i = 0; i < IM; i++)
#pragma unroll
      for (int r = 0; r < 4; r++) {
        long row = baseRow + i * 16 + r;
#pragma unroll
        for (int j = 0; j < IN; j++)
          Cf[row * ldc + baseCol + j * 16] = acc[i][j][r] * alpha;
      }
  }
}

// ---------------------------------------------------------------------------

extern "C" void kernel_launch(void* const* d_in, const int* in_sizes, int n_in,
                              void* d_out, int out_size, void* d_ws,
                              size_t ws_size, hipStream_t stream) {
  const float* x  = (const float*)d_in[0];  // (8, 2048, 256)
  const float* e  = (const float*)d_in[1];  // (2048, 256)
  const float* Wq = (const float*)d_in[2];  // (512, 512)
  const float* Wk = (const float*)d_in[3];  // (512, 512)
  float* out = (float*)d_out;               // (8, 2048, 256)

  char* ws = (char*)d_ws;
  size_t off = 0;
  auto alloc = [&](size_t bytes) {
    void* p = ws + off;
    off += (bytes + 255) & ~(size_t)255;
    return p;
  };

  __hip_bfloat16* xe  = (__hip_bfloat16*)alloc((size_t)NB * NN * DD * 2);      // 16.8 MB
  __hip_bfloat16* Wqk = (__hip_bfloat16*)alloc((size_t)2 * DD * DD * 2);       // 1 MB
  __hip_bfloat16* VT  = (__hip_bfloat16*)alloc((size_t)NB * DIM_X * NN * 2);   // 8.4 MB
  __hip_bfloat16* Qb  = (__hip_bfloat16*)alloc((size_t)NB * NN * DD * 2);      // 16.8 MB
  __hip_bfloat16* KT  = (__hip_bfloat16*)alloc((size_t)NB * DD * NN * 2);      // 16.8 MB
  __hip_bfloat16* PT  = (__hip_bfloat16*)alloc((size_t)NB * DIM_X * DD * 2);   // 2 MB

  // --- prep ---
  pack_xv<<<dim3(DIM_X / 32, NN / 32, NB), dim3(32, 8), 0, stream>>>(x, xe, VT);
  pack_e<<<(NB * NN * DIM_X / 4) / 256, 256, 0, stream>>>(e, xe);
  pack_w<<<512, 256, 0, stream>>>(Wq, Wk, Wqk);

  // --- G1a: Q(16384x512) = xe(16384x512) @ Wq(512x512)^T ---
  gemm_bt<128, 128, 64, 64, true>
      <<<dim3(DD / 128, (NB * NN) / 128, 1), 256, 0, stream>>>(
          xe, Wqk, Qb, DD, DD, DD, DD, 0, 0, 0, 1.0f);

  // --- G1b (batched): KT_b(512x2048) = Wk(512x512) @ xe_b(2048x512)^T ---
  gemm_bt<128, 128, 64, 64, true>
      <<<dim3(NN / 128, DD / 128, NB), 256, 0, stream>>>(
          Wqk + DD * DD, xe, KT, DD, DD, DD, NN, 0, (long)NN * DD,
          (long)DD * NN, 1.0f);

  // --- G2 (batched): PT_b(256x512) = SCALE * VT_b(256x2048) @ KT_b(512x2048)^T
  //     = SCALE * (V^T K)  [the KᵀV reassociation: tiny inner product matrix]
  gemm_bt<64, 64, 32, 32, true>
      <<<dim3(DD / 64, DIM_X / 64, NB), 256, 0, stream>>>(
          VT, KT, PT, NN, NN, NN, DD, (long)DIM_X * NN, (long)DD * NN,
          (long)DIM_X * DD, SCALE);

  // --- G3 (batched): out_b(2048x256) = Q_b(2048x512) @ PT_b(256x512)^T, fp32
  gemm_bt<128, 128, 64, 64, false>
      <<<dim3(DIM_X / 128, NN / 128, NB), 256, 0, stream>>>(
          Qb, PT, out, DD, DD, DD, DIM_X, (long)NN * DD, (long)DIM_X * DD,
          (long)NN * DIM_X, 1.0f);
}

// Round 3
// 128.168 us; speedup vs baseline: 1.7257x; 1.2033x over previous
//
#include <hip/hip_runtime.h>
#include <hip/hip_bf16.h>

// Problem constants
#define DIM_X 256
#define DIM_E 256
#define DD    512          // DIM_X + DIM_E
#define NB    8            // batch
#define NN    2048         // sequence
#define SCALE 0.044194173824159216f   // (DIM_X+DIM_E)^-0.5

typedef __attribute__((ext_vector_type(8))) __bf16 bf16x8;
typedef __attribute__((ext_vector_type(4))) float  f32x4;

// async global->LDS 16B copy. LDS dest must be wave-uniform base + lane*16.
__device__ __forceinline__ void async_lds16(const void* g, void* l) {
  using u32_as3 = __attribute__((address_space(3))) unsigned int;
  using u32_as1 = const __attribute__((address_space(1))) unsigned int;
  __builtin_amdgcn_global_load_lds(
      reinterpret_cast<u32_as1*>(reinterpret_cast<unsigned long long>(g)),
      reinterpret_cast<u32_as3*>(static_cast<unsigned int>(
          reinterpret_cast<unsigned long long>(l))),
      16, 0, 0);
}

// ---------------------------------------------------------------------------
// Prep kernels
// ---------------------------------------------------------------------------

// Reads x ONCE; writes xb (bf16 straight copy) and VT[b][t][n] (transpose).
__global__ __launch_bounds__(256) void pack_xv(const float* __restrict__ x,
                                               __hip_bfloat16* __restrict__ xb,
                                               __hip_bfloat16* __restrict__ VT) {
  __shared__ float tile[32][33];
  const int tx = threadIdx.x, ty = threadIdx.y;
  const int b = blockIdx.z, n0 = blockIdx.y * 32, t0 = blockIdx.x * 32;
  const float* xs = x + ((long)b * NN + n0) * DIM_X + t0;
#pragma unroll
  for (int k = 0; k < 4; k++) {
    int i = ty + k * 8;
    tile[i][tx] = xs[(long)i * DIM_X + tx];
  }
  __syncthreads();
#pragma unroll
  for (int k = 0; k < 4; k++) {
    int i = ty + k * 8;
    xb[((long)b * NN + n0 + i) * DIM_X + t0 + tx] =
        __float2bfloat16(tile[i][tx]);
    VT[((long)b * DIM_X + t0 + i) * NN + n0 + tx] =
        __float2bfloat16(tile[tx][i]);
  }
}

// One kernel for all small preps:
//  blocks [0,512):    e (2048x256) -> eb (bf16 straight) + ET (bf16 transpose)
//  blocks [512,768):  Wq (512x512) -> WqT (bf16 transpose)
//  blocks [768,1024): Wk (512x512) -> WkT (bf16 transpose)
__global__ __launch_bounds__(256) void pack_misc(
    const float* __restrict__ e, const float* __restrict__ Wq,
    const float* __restrict__ Wk, __hip_bfloat16* __restrict__ eb,
    __hip_bfloat16* __restrict__ ET, __hip_bfloat16* __restrict__ WqT,
    __hip_bfloat16* __restrict__ WkT) {
  __shared__ float tile[32][33];
  const int tx = threadIdx.x, ty = threadIdx.y;
  const int bx = blockIdx.x;

  const float* src;
  __hip_bfloat16* dstT;
  int r0, c0, rows, straight = 0;
  if (bx < 512) {
    r0 = (bx >> 3) * 32; c0 = (bx & 7) * 32;
    src = e; dstT = ET; rows = NN; straight = 1;
  } else if (bx < 768) {
    int i = bx - 512;
    r0 = (i >> 4) * 32; c0 = (i & 15) * 32;
    src = Wq; dstT = WqT; rows = DD;
  } else {
    int i = bx - 768;
    r0 = (i >> 4) * 32; c0 = (i & 15) * 32;
    src = Wk; dstT = WkT; rows = DD;
  }
  const int ld = (bx < 512) ? DIM_E : DD;
  const int ldT = rows;
#pragma unroll
  for (int k = 0; k < 4; k++) {
    int i = ty + k * 8;
    tile[i][tx] = src[(long)(r0 + i) * ld + c0 + tx];
  }
  __syncthreads();
#pragma unroll
  for (int k = 0; k < 4; k++) {
    int i = ty + k * 8;
    dstT[(long)(c0 + i) * ldT + r0 + tx] = __float2bfloat16(tile[tx][i]);
    if (straight)
      eb[(long)(r0 + i) * DIM_E + c0 + tx] = __float2bfloat16(tile[i][tx]);
  }
}

// ---------------------------------------------------------------------------
// B-transposed bf16 GEMM: C[M,N] = alpha * A[M,K] * B[N,K]^T
// Block tile BMxBN, 4 waves (256 thr), wave tile WTMxWTN, 16x16x32 bf16 MFMA,
// K-tile BKt (32 or 64), global_load_lds width-16 staging, XOR-swizzled LDS.
// SPLIT==1: A columns k>=256 come from A2 (shared, no batch stride).
// SPLIT==2: B rows    n>=256 come from B2 (shared, no batch stride).
// Both selects are uniform (tiles divide 256).
// ---------------------------------------------------------------------------
template <int BM, int BN, int BKt, int WTM, int WTN, bool OUT_BF16, int SPLIT>
__global__ __launch_bounds__(256) void gemm_bt(
    const __hip_bfloat16* __restrict__ A,
    const __hip_bfloat16* __restrict__ A2,
    const __hip_bfloat16* __restrict__ B,
    const __hip_bfloat16* __restrict__ B2,
    void* __restrict__ Cv,
    int K, int lda, int lda2, int ldb, int ldb2, int ldc,
    long strideA, long strideB, long strideC, float alpha) {
  constexpr int IM  = WTM / 16;
  constexpr int IN  = WTN / 16;
  constexpr int NWC = BN / WTN;      // waves along N
  constexpr int CPT = BKt / 8;       // 16B chunks per row
  constexpr int CA  = BM * CPT;
  constexpr int CB  = BN * CPT;
  constexpr int KS  = BKt / 32;      // MFMA k-steps per staged tile

  __shared__ __hip_bfloat16 sA[BM * BKt];
  __shared__ __hip_bfloat16 sB[BN * BKt];

  const int tid  = threadIdx.x;
  const int lane = tid & 63;
  const int wave = tid >> 6;
  const int lm   = lane & 15;
  const int quad = lane >> 4;
  const int wm   = (wave / NWC) * WTM;
  const int wn   = (wave % NWC) * WTN;
  const long bz  = blockIdx.z;

  // swizzle: BKt=32 -> (r>>1)&3 (row stride 64B, 2-row bank phase);
  //          BKt=64 -> r&7      (row stride 128B, full bank span)
  auto swz = [](int r) { return (BKt == 32) ? ((r >> 1) & 3) : (r & 7); };

  const __hip_bfloat16* Abase = A + bz * strideA + (long)blockIdx.y * BM * lda;
  const __hip_bfloat16* Abase2 =
      (SPLIT == 1) ? (A2 + (long)blockIdx.y * BM * lda2) : nullptr;

  const __hip_bfloat16* Bbase;
  int ldbx;
  if (SPLIT == 2) {
    const int n0 = blockIdx.x * BN;
    if (n0 < 256) { Bbase = B + bz * strideB + (long)n0 * ldb; ldbx = ldb; }
    else          { Bbase = B2 + (long)(n0 - 256) * ldb2;      ldbx = ldb2; }
  } else {
    Bbase = B + bz * strideB + (long)blockIdx.x * BN * ldb;
    ldbx = ldb;
  }

  f32x4 acc[IM][IN];
#pragma unroll
  for (int i = 0; i < IM; i++)
#pragma unroll
    for (int j = 0; j < IN; j++) acc[i][j] = (f32x4){0.f, 0.f, 0.f, 0.f};

  for (int k0 = 0; k0 < K; k0 += BKt) {
    const __hip_bfloat16* Ak;
    int kloc, ldax;
    if (SPLIT == 1 && k0 >= 256) { Ak = Abase2; kloc = k0 - 256; ldax = lda2; }
    else                         { Ak = Abase;  kloc = k0;       ldax = lda; }

#pragma unroll
    for (int c = tid; c < CA; c += 256) {
      int row = c / CPT;
      int cb  = (c % CPT) ^ swz(row);
      async_lds16(Ak + (long)row * ldax + kloc + cb * 8, sA + (size_t)c * 8);
    }
#pragma unroll
    for (int c = tid; c < CB; c += 256) {
      int row = c / CPT;
      int cb  = (c % CPT) ^ swz(row);
      async_lds16(Bbase + (long)row * ldbx + k0 + cb * 8, sB + (size_t)c * 8);
    }
    __syncthreads();  // drains vmcnt (global_load_lds)

    bf16x8 af[KS][IM], bfr[KS][IN];
#pragma unroll
    for (int s = 0; s < KS; s++) {
#pragma unroll
      for (int i = 0; i < IM; i++) {
        int r  = wm + i * 16 + lm;
        int cb = (s * 4 + quad) ^ swz(r);
        af[s][i] = *(const bf16x8*)&sA[r * BKt + cb * 8];
      }
#pragma unroll
      for (int j = 0; j < IN; j++) {
        int r  = wn + j * 16 + lm;
        int cb = (s * 4 + quad) ^ swz(r);
        bfr[s][j] = *(const bf16x8*)&sB[r * BKt + cb * 8];
      }
    }

#pragma unroll
    for (int s = 0; s < KS; s++)
#pragma unroll
      for (int i = 0; i < IM; i++)
#pragma unroll
        for (int j = 0; j < IN; j++)
          acc[i][j] = __builtin_amdgcn_mfma_f32_16x16x32_bf16(
              af[s][i], bfr[s][j], acc[i][j], 0, 0, 0);
    __syncthreads();
  }

  // C/D layout (16x16): col = lane&15, row = (lane>>4)*4 + reg  [m89-verified]
  const long baseRow = (long)blockIdx.y * BM + wm + quad * 4;
  const long baseCol = (long)blockIdx.x * BN + wn + lm;
  if (OUT_BF16) {
    __hip_bfloat16* Cb = (__hip_bfloat16*)Cv + bz * strideC;
#pragma unroll
    for (int i = 0; i < IM; i++)
#pragma unroll
      for (int r = 0; r < 4; r++) {
        long row = baseRow + i * 16 + r;
#pragma unroll
        for (int j = 0; j < IN; j++)
          Cb[row * ldc + baseCol + j * 16] =
              __float2bfloat16(acc[i][j][r] * alpha);
      }
  } else {
    float* Cf = (float*)Cv + bz * strideC;
#pragma unroll
    for (int i = 0; i < IM; i++)
#pragma unroll
      for (int r = 0; r < 4; r++) {
        long row = baseRow + i * 16 + r;
#pragma unroll
        for (int j = 0; j < IN; j++)
          Cf[row * ldc + baseCol + j * 16] = acc[i][j][r] * alpha;
      }
  }
}

// ---------------------------------------------------------------------------

extern "C" void kernel_launch(void* const* d_in, const int* in_sizes, int n_in,
                              void* d_out, int out_size, void* d_ws,
                              size_t ws_size, hipStream_t stream) {
  const float* x  = (const float*)d_in[0];  // (8, 2048, 256)
  const float* e  = (const float*)d_in[1];  // (2048, 256)
  const float* Wq = (const float*)d_in[2];  // (512, 512)
  const float* Wk = (const float*)d_in[3];  // (512, 512)
  float* out = (float*)d_out;               // (8, 2048, 256)

  char* ws = (char*)d_ws;
  size_t off = 0;
  auto alloc = [&](size_t bytes) {
    void* p = ws + off;
    off += (bytes + 255) & ~(size_t)255;
    return p;
  };

  __hip_bfloat16* xb  = (__hip_bfloat16*)alloc((size_t)NB * NN * DIM_X * 2);  // 8.4 MB
  __hip_bfloat16* VT  = (__hip_bfloat16*)alloc((size_t)NB * DIM_X * NN * 2);  // 8.4 MB
  __hip_bfloat16* eb  = (__hip_bfloat16*)alloc((size_t)NN * DIM_E * 2);       // 1 MB
  __hip_bfloat16* ET  = (__hip_bfloat16*)alloc((size_t)DIM_E * NN * 2);       // 1 MB
  __hip_bfloat16* WqT = (__hip_bfloat16*)alloc((size_t)DD * DD * 2);          // 0.5 MB
  __hip_bfloat16* WkT = (__hip_bfloat16*)alloc((size_t)DD * DD * 2);          // 0.5 MB
  __hip_bfloat16* W2T = (__hip_bfloat16*)alloc((size_t)DD * DD * 2);          // 0.5 MB
  __hip_bfloat16* M   = (__hip_bfloat16*)alloc((size_t)NB * DIM_X * DD * 2);  // 2 MB
  __hip_bfloat16* R   = (__hip_bfloat16*)alloc((size_t)NB * DIM_X * DD * 2);  // 2 MB

  // --- prep ---
  pack_xv<<<dim3(DIM_X / 32, NN / 32, NB), dim3(32, 8), 0, stream>>>(x, xb, VT);
  pack_misc<<<1024, dim3(32, 8), 0, stream>>>(e, Wq, Wk, eb, ET, WqT, WkT);

  // --- W2T(512x512) = WqT @ WkT^T  ( = (Wk^T Wq)^T, batch-invariant ) ---
  gemm_bt<64, 64, 64, 32, 32, true, 0>
      <<<dim3(DD / 64, DD / 64, 1), 256, 0, stream>>>(
          WqT, nullptr, WkT, nullptr, W2T, DD, DD, 0, DD, 0, DD, 0, 0, 0,
          1.0f);

  // --- M_b(256x512) = VT_b @ [VT_b ; ET]^T  (K = 2048) ---
  gemm_bt<64, 64, 64, 32, 32, true, 2>
      <<<dim3(DD / 64, DIM_X / 64, NB), 256, 0, stream>>>(
          VT, nullptr, VT, ET, M, NN, NN, 0, NN, NN, DD,
          (long)DIM_X * NN, (long)DIM_X * NN, (long)DIM_X * DD, 1.0f);

  // --- R_b(256x512) = SCALE * M_b @ W2T^T  ( = SCALE * M_b W2 ) ---
  gemm_bt<64, 64, 64, 32, 32, true, 0>
      <<<dim3(DD / 64, DIM_X / 64, NB), 256, 0, stream>>>(
          M, nullptr, W2T, nullptr, R, DD, DD, 0, DD, 0, DD,
          (long)DIM_X * DD, 0, (long)DIM_X * DD, SCALE);

  // --- out_b(2048x256) = [xb_b | eb] @ R_b^T  (fp32, K = 512) ---
  gemm_bt<128, 128, 32, 64, 64, false, 1>
      <<<dim3(DIM_X / 128, NN / 128, NB), 256, 0, stream>>>(
          xb, eb, R, nullptr, out, DD, DIM_X, DIM_X, DD, 0, DIM_X,
          (long)NN * DIM_X, (long)DIM_X * DD, (long)NN * DIM_X, 1.0f);
}